// Round 2
// baseline (1692.393 us; speedup 1.0000x reference)
//
#include <hip/hip_runtime.h>
#include <math.h>

#define B_ 8
#define C_ 256
#define N_ 2048

// ---------------------------------------------------------------------------
// Kernel 1: fused QKV projection.
//   Q[b,o,n] = sum_c Wq[o,c] * x[b,c,n] + bq[o]   (same for K, V)
// Grid: (N/64, C/64, B), 256 threads. Each block: 64(o) x 64(n) tile of all
// three outputs. x tile staged once in LDS, reused for Wq/Wk/Wv.
// ---------------------------------------------------------------------------
__global__ __launch_bounds__(256) void qkv_k(
    const float* __restrict__ x,
    const float* __restrict__ Wq, const float* __restrict__ bq,
    const float* __restrict__ Wk, const float* __restrict__ bk,
    const float* __restrict__ Wv, const float* __restrict__ bv,
    float* __restrict__ Q, float* __restrict__ K, float* __restrict__ V)
{
    const int b   = blockIdx.z;
    const int o0  = blockIdx.y * 64;
    const int n0  = blockIdx.x * 64;
    const int tid = threadIdx.x;
    const int tx  = tid & 15;       // n micro-tile
    const int ty  = tid >> 4;       // o micro-tile

    // 68-float stride: 272B rows -> 16B aligned, breaks power-of-2 conflicts
    __shared__ float xs[16][68];
    __shared__ float wqs[16][68], wks[16][68], wvs[16][68];  // [k][o]

    float aq[4][4] = {}, ak[4][4] = {}, av[4][4] = {};

    const float* xb = x + (size_t)b * C_ * N_;

    const int xr = tid >> 4;          // 0..15  (k row of x chunk)
    const int xc = (tid & 15) * 4;    // 0..60  (n col)
    const int wr = tid >> 2;          // 0..63  (o row of W chunk)
    const int wc = (tid & 3) * 4;     // 0..12  (k col)

    for (int k0 = 0; k0 < C_; k0 += 16) {
        // issue global loads early (overlap with previous compute)
        float4 xv = *(const float4*)(xb + (size_t)(k0 + xr) * N_ + n0 + xc);
        float4 q4 = *(const float4*)(Wq + (size_t)(o0 + wr) * C_ + k0 + wc);
        float4 k4 = *(const float4*)(Wk + (size_t)(o0 + wr) * C_ + k0 + wc);
        float4 v4 = *(const float4*)(Wv + (size_t)(o0 + wr) * C_ + k0 + wc);
        __syncthreads();   // previous iteration's LDS reads done
        *(float4*)&xs[xr][xc] = xv;
        wqs[wc+0][wr] = q4.x; wqs[wc+1][wr] = q4.y; wqs[wc+2][wr] = q4.z; wqs[wc+3][wr] = q4.w;
        wks[wc+0][wr] = k4.x; wks[wc+1][wr] = k4.y; wks[wc+2][wr] = k4.z; wks[wc+3][wr] = k4.w;
        wvs[wc+0][wr] = v4.x; wvs[wc+1][wr] = v4.y; wvs[wc+2][wr] = v4.z; wvs[wc+3][wr] = v4.w;
        __syncthreads();

        #pragma unroll
        for (int k = 0; k < 16; ++k) {
            float xl[4], ql[4], kl[4], vl[4];
            *(float4*)xl = *(const float4*)&xs[k][tx*4];    // 2-way (free)
            *(float4*)ql = *(const float4*)&wqs[k][ty*4];   // broadcast-ish
            *(float4*)kl = *(const float4*)&wks[k][ty*4];
            *(float4*)vl = *(const float4*)&wvs[k][ty*4];
            #pragma unroll
            for (int i = 0; i < 4; ++i)
                #pragma unroll
                for (int j = 0; j < 4; ++j) {
                    aq[i][j] += ql[i] * xl[j];
                    ak[i][j] += kl[i] * xl[j];
                    av[i][j] += vl[i] * xl[j];
                }
        }
    }

    #pragma unroll
    for (int i = 0; i < 4; ++i) {
        const int o = o0 + ty*4 + i;
        const float bqv = bq[o], bkv = bk[o], bvv = bv[o];
        const size_t base = ((size_t)b * C_ + o) * N_ + n0 + tx*4;
        float4 oq, ok, ov;
        oq.x=aq[i][0]+bqv; oq.y=aq[i][1]+bqv; oq.z=aq[i][2]+bqv; oq.w=aq[i][3]+bqv;
        ok.x=ak[i][0]+bkv; ok.y=ak[i][1]+bkv; ok.z=ak[i][2]+bkv; ok.w=ak[i][3]+bkv;
        ov.x=av[i][0]+bvv; ov.y=av[i][1]+bvv; ov.z=av[i][2]+bvv; ov.w=av[i][3]+bvv;
        *(float4*)(Q + base) = oq;
        *(float4*)(K + base) = ok;
        *(float4*)(V + base) = ov;
    }
}

// ---------------------------------------------------------------------------
// Kernel 2: flash attention + residual.
//   S = Q^T K * 1/16 ; P = softmax_m(S) ; out[c,n] = sum_m P[n,m] V[c,m] + x
// Grid: (N/64, B), 256 threads. Per block: 64 query rows (n), loop over all
// 32 key tiles (m). n lives on ty (4 rows/thread, row group inside one wave
// -> running max/sum fully in registers, no cross-wave comms).
// Out acc: 256 c x 64 n -> 64 f32/thread as [g][i(n)][j(c)].
// ---------------------------------------------------------------------------
__global__ __launch_bounds__(256) void attn_k(
    const float* __restrict__ Qg, const float* __restrict__ Kg,
    const float* __restrict__ Vg, const float* __restrict__ x,
    float* __restrict__ out)
{
    const int b   = blockIdx.y;
    const int n0  = blockIdx.x * 64;
    const int tid = threadIdx.x;
    const int tx  = tid & 15;       // m (S phase) / c' (PV phase)
    const int ty  = tid >> 4;       // n rows (both phases)

    __shared__ float qs[32][68];    // [k][n]
    __shared__ float ks[32][68];    // [k][m]
    __shared__ float ps[64][68];    // [n][m]
    __shared__ float vst[64][68];   // [m][c']  (transposed V tile; also epilogue staging)

    float oacc[4][4][4] = {};       // [g][i=n][j=c]
    float mrun[4] = {-1e30f, -1e30f, -1e30f, -1e30f};
    float lrun[4] = {0.f, 0.f, 0.f, 0.f};

    const float* Qb = Qg + (size_t)b * C_ * N_;
    const float* Kb = Kg + (size_t)b * C_ * N_;
    const float* Vb = Vg + (size_t)b * C_ * N_;

    const int sr = tid >> 4;          // 0..15
    const int sc = (tid & 15) * 4;

    for (int m0 = 0; m0 < N_; m0 += 64) {
        // ---- S = Q^T K over C, staged in 32-row chunks ----
        float s[4][4] = {};
        for (int k0 = 0; k0 < C_; k0 += 32) {
            float4 qv0 = *(const float4*)(Qb + (size_t)(k0 + sr     ) * N_ + n0 + sc);
            float4 qv1 = *(const float4*)(Qb + (size_t)(k0 + sr + 16) * N_ + n0 + sc);
            float4 kv0 = *(const float4*)(Kb + (size_t)(k0 + sr     ) * N_ + m0 + sc);
            float4 kv1 = *(const float4*)(Kb + (size_t)(k0 + sr + 16) * N_ + m0 + sc);
            __syncthreads();
            *(float4*)&qs[sr     ][sc] = qv0;
            *(float4*)&qs[sr + 16][sc] = qv1;
            *(float4*)&ks[sr     ][sc] = kv0;
            *(float4*)&ks[sr + 16][sc] = kv1;
            __syncthreads();
            #pragma unroll
            for (int k = 0; k < 32; ++k) {
                float a[4], bm[4];
                *(float4*)a  = *(const float4*)&qs[k][ty*4];  // broadcast over tx
                *(float4*)bm = *(const float4*)&ks[k][tx*4];  // 2-way (free)
                #pragma unroll
                for (int i = 0; i < 4; ++i)
                    #pragma unroll
                    for (int j = 0; j < 4; ++j)
                        s[i][j] += a[i] * bm[j];
            }
        }

        // ---- online softmax (row n = ty*4+i; reduce across tx lanes) ----
        float alpha[4];
        #pragma unroll
        for (int i = 0; i < 4; ++i) {
            #pragma unroll
            for (int j = 0; j < 4; ++j) s[i][j] *= 0.0625f;   // 1/sqrt(256)
            float m_ = fmaxf(fmaxf(s[i][0], s[i][1]), fmaxf(s[i][2], s[i][3]));
            #pragma unroll
            for (int sft = 1; sft < 16; sft <<= 1)
                m_ = fmaxf(m_, __shfl_xor(m_, sft, 16));
            const float mnew = fmaxf(mrun[i], m_);
            alpha[i] = __expf(mrun[i] - mnew);
            float r = 0.f;
            #pragma unroll
            for (int j = 0; j < 4; ++j) {
                const float p = __expf(s[i][j] - mnew);
                s[i][j] = p;
                r += p;
            }
            #pragma unroll
            for (int sft = 1; sft < 16; sft <<= 1)
                r += __shfl_xor(r, sft, 16);
            lrun[i] = alpha[i] * lrun[i] + r;
            mrun[i] = mnew;
        }

        // P -> LDS
        #pragma unroll
        for (int i = 0; i < 4; ++i) {
            float4 pv; pv.x = s[i][0]; pv.y = s[i][1]; pv.z = s[i][2]; pv.w = s[i][3];
            *(float4*)&ps[ty*4 + i][tx*4] = pv;
        }

        // rescale accumulator (alpha indexed by i == n row, already in regs)
        #pragma unroll
        for (int g = 0; g < 4; ++g)
            #pragma unroll
            for (int i = 0; i < 4; ++i)
                #pragma unroll
                for (int j = 0; j < 4; ++j)
                    oacc[g][i][j] *= alpha[i];

        // ---- PV: out[c,n] += sum_m P[n,m] * V[c,m], c in 4 chunks of 64 ----
        #pragma unroll 1
        for (int g = 0; g < 4; ++g) {
            __syncthreads();   // prev reads of vst/ps done before overwrite
            #pragma unroll
            for (int p = 0; p < 4; ++p) {     // stage V[64g..][m0..] transposed
                const int mo = p*16 + (tid & 3) * 4;
                const int r  = tid >> 2;
                float4 vv = *(const float4*)(Vb + (size_t)(g*64 + r) * N_ + m0 + mo);
                vst[mo+0][r] = vv.x; vst[mo+1][r] = vv.y;
                vst[mo+2][r] = vv.z; vst[mo+3][r] = vv.w;
            }
            __syncthreads();
            #pragma unroll
            for (int m4 = 0; m4 < 16; ++m4) {
                float pp[4][4], vv[4][4];
                #pragma unroll
                for (int i = 0; i < 4; ++i)
                    *(float4*)pp[i] = *(const float4*)&ps[ty*4 + i][m4*4]; // broadcast
                #pragma unroll
                for (int u = 0; u < 4; ++u)
                    *(float4*)vv[u] = *(const float4*)&vst[m4*4 + u][tx*4]; // 2-way
                #pragma unroll
                for (int i = 0; i < 4; ++i)
                    #pragma unroll
                    for (int j = 0; j < 4; ++j) {
                        float acc = oacc[g][i][j];
                        acc += pp[i][0] * vv[0][j];
                        acc += pp[i][1] * vv[1][j];
                        acc += pp[i][2] * vv[2][j];
                        acc += pp[i][3] * vv[3][j];
                        oacc[g][i][j] = acc;
                    }
            }
        }
    }

    // ---- epilogue: /l, +x, coalesced store via LDS transpose ----
    float recl[4];
    #pragma unroll
    for (int i = 0; i < 4; ++i) recl[i] = 1.f / lrun[i];

    #pragma unroll 1
    for (int g = 0; g < 4; ++g) {
        __syncthreads();
        #pragma unroll
        for (int i = 0; i < 4; ++i)
            #pragma unroll
            for (int j = 0; j < 4; ++j)
                vst[tx*4 + j][ty*4 + i] = oacc[g][i][j] * recl[i];  // [c'][n]
        __syncthreads();
        #pragma unroll
        for (int p = 0; p < 4; ++p) {
            const int r  = p*16 + (tid >> 4);     // c' 0..63
            const int c4 = (tid & 15) * 4;        // n
            float4 t = *(const float4*)&vst[r][c4];
            const size_t gidx = ((size_t)b * C_ + g*64 + r) * N_ + n0 + c4;
            float4 xv = *(const float4*)(x + gidx);
            t.x += xv.x; t.y += xv.y; t.z += xv.z; t.w += xv.w;
            *(float4*)(out + gidx) = t;
        }
    }
}

// ---------------------------------------------------------------------------
extern "C" void kernel_launch(void* const* d_in, const int* in_sizes, int n_in,
                              void* d_out, int out_size, void* d_ws, size_t ws_size,
                              hipStream_t stream) {
    const float* x  = (const float*)d_in[0];
    const float* Wq = (const float*)d_in[1];
    const float* bq = (const float*)d_in[2];
    const float* Wk = (const float*)d_in[3];
    const float* bk = (const float*)d_in[4];
    const float* Wv = (const float*)d_in[5];
    const float* bv = (const float*)d_in[6];
    float* outp = (float*)d_out;

    const size_t plane = (size_t)B_ * C_ * N_;   // 4,194,304 floats
    float* Q = (float*)d_ws;
    float* K = Q + plane;
    float* V = K + plane;
    // requires ws_size >= 3 * plane * 4 = 50,331,648 bytes

    dim3 g1(N_/64, C_/64, B_);
    qkv_k<<<g1, 256, 0, stream>>>(x, Wq, bq, Wk, bk, Wv, bv, Q, K, V);

    dim3 g2(N_/64, B_);
    attn_k<<<g2, 256, 0, stream>>>(Q, K, V, x, outp);
}

// Round 5
// 386.262 us; speedup vs baseline: 4.3815x; 4.3815x over previous
//
#include <hip/hip_runtime.h>
#include <math.h>

#define B_ 8
#define C_ 256
#define N_ 2048

typedef __attribute__((ext_vector_type(8))) short bf16x8;
typedef __attribute__((ext_vector_type(4))) float f32x4;
typedef unsigned int u32;
typedef unsigned short u16;

#define MFMA(a, b, c) __builtin_amdgcn_mfma_f32_16x16x32_bf16(a, b, c, 0, 0, 0)

__device__ __forceinline__ u16 f2bf(float f) {            // RNE float->bf16
    u32 u = __float_as_uint(f);
    return (u16)((u + 0x7FFFu + ((u >> 16) & 1u)) >> 16);
}
__device__ __forceinline__ bf16x8 ldg8(const u16* p) {
    return *reinterpret_cast<const bf16x8*>(p);
}

// ---------------------------------------------------------------------------
// Kernel 1: fused QKV projection -> bf16 planes.
//   Qt : [B][N][C] bf16 (pre-scaled by 1/16),  Kt : [B][N][C],  V : [B][C][N]
// Grid (N/64, C/64, B), 256 threads, 64x64 tiles, fp32 accumulate.
// ---------------------------------------------------------------------------
__global__ __launch_bounds__(256) void qkv_k(
    const float* __restrict__ x,
    const float* __restrict__ Wq, const float* __restrict__ bq,
    const float* __restrict__ Wk, const float* __restrict__ bk,
    const float* __restrict__ Wv, const float* __restrict__ bv,
    u16* __restrict__ qtp, u16* __restrict__ ktp, u16* __restrict__ vtp)
{
    const int b   = blockIdx.z;
    const int o0  = blockIdx.y * 64;
    const int n0  = blockIdx.x * 64;
    const int tid = threadIdx.x;
    const int tx  = tid & 15;
    const int ty  = tid >> 4;

    __shared__ float xs[16][68];
    __shared__ float wqs[16][68], wks[16][68], wvs[16][68];
    __shared__ float tb[64][68];            // transpose staging

    float aq[4][4] = {}, ak[4][4] = {}, av[4][4] = {};

    const float* xb = x + (size_t)b * C_ * N_;
    const int xr = tid >> 4, xc = (tid & 15) * 4;
    const int wr = tid >> 2, wc = (tid & 3) * 4;

    for (int k0 = 0; k0 < C_; k0 += 16) {
        float4 xv = *(const float4*)(xb + (size_t)(k0 + xr) * N_ + n0 + xc);
        float4 q4 = *(const float4*)(Wq + (size_t)(o0 + wr) * C_ + k0 + wc);
        float4 k4 = *(const float4*)(Wk + (size_t)(o0 + wr) * C_ + k0 + wc);
        float4 v4 = *(const float4*)(Wv + (size_t)(o0 + wr) * C_ + k0 + wc);
        __syncthreads();   // previous iteration's LDS reads done
        *(float4*)&xs[xr][xc] = xv;
        wqs[wc+0][wr] = q4.x; wqs[wc+1][wr] = q4.y; wqs[wc+2][wr] = q4.z; wqs[wc+3][wr] = q4.w;
        wks[wc+0][wr] = k4.x; wks[wc+1][wr] = k4.y; wks[wc+2][wr] = k4.z; wks[wc+3][wr] = k4.w;
        wvs[wc+0][wr] = v4.x; wvs[wc+1][wr] = v4.y; wvs[wc+2][wr] = v4.z; wvs[wc+3][wr] = v4.w;
        __syncthreads();

        #pragma unroll
        for (int k = 0; k < 16; ++k) {
            float xl[4], ql_[4], kl_[4], vl_[4];
            *(float4*)xl  = *(const float4*)&xs[k][tx*4];
            *(float4*)ql_ = *(const float4*)&wqs[k][ty*4];
            *(float4*)kl_ = *(const float4*)&wks[k][ty*4];
            *(float4*)vl_ = *(const float4*)&wvs[k][ty*4];
            #pragma unroll
            for (int i = 0; i < 4; ++i)
                #pragma unroll
                for (int j = 0; j < 4; ++j) {
                    aq[i][j] += ql_[i] * xl[j];
                    ak[i][j] += kl_[i] * xl[j];
                    av[i][j] += vl_[i] * xl[j];
                }
        }
    }

    // ---- V: bf16 store, [B][C][N] ----
    #pragma unroll
    for (int i = 0; i < 4; ++i) {
        const int o = o0 + ty*4 + i;
        const float bvv = bv[o];
        const size_t base = ((size_t)b * C_ + o) * N_ + n0 + tx*4;
        u16 h[4];
        #pragma unroll
        for (int j = 0; j < 4; ++j) h[j] = f2bf(av[i][j] + bvv);
        uint2 hv;
        hv.x = (u32)h[0] | ((u32)h[1] << 16);
        hv.y = (u32)h[2] | ((u32)h[3] << 16);
        *reinterpret_cast<uint2*>(vtp + base) = hv;
    }

    // ---- Q: transpose to [B][N][C], pre-scaled by 1/16 ----
    __syncthreads();
    #pragma unroll
    for (int i = 0; i < 4; ++i) {
        const float bqv = bq[o0 + ty*4 + i];
        #pragma unroll
        for (int j = 0; j < 4; ++j)
            tb[tx*4 + j][ty*4 + i] = (aq[i][j] + bqv) * 0.0625f;
    }
    __syncthreads();
    {
        const int r = tid >> 2, och = (tid & 3) * 16;
        float vals[16];
        #pragma unroll
        for (int u = 0; u < 4; ++u)
            *(float4*)&vals[u*4] = *(const float4*)&tb[r][och + u*4];
        u32 hw[8];
        #pragma unroll
        for (int e = 0; e < 8; ++e)
            hw[e] = (u32)f2bf(vals[2*e]) | ((u32)f2bf(vals[2*e+1]) << 16);
        const size_t qb = ((size_t)b * N_ + n0 + r) * C_ + o0 + och;
        reinterpret_cast<uint4*>(qtp + qb)[0] = make_uint4(hw[0], hw[1], hw[2], hw[3]);
        reinterpret_cast<uint4*>(qtp + qb)[1] = make_uint4(hw[4], hw[5], hw[6], hw[7]);
    }

    // ---- K: transpose to [B][N][C] ----
    __syncthreads();
    #pragma unroll
    for (int i = 0; i < 4; ++i) {
        const float bkv = bk[o0 + ty*4 + i];
        #pragma unroll
        for (int j = 0; j < 4; ++j)
            tb[tx*4 + j][ty*4 + i] = ak[i][j] + bkv;
    }
    __syncthreads();
    {
        const int r = tid >> 2, och = (tid & 3) * 16;
        float vals[16];
        #pragma unroll
        for (int u = 0; u < 4; ++u)
            *(float4*)&vals[u*4] = *(const float4*)&tb[r][och + u*4];
        u32 hw[8];
        #pragma unroll
        for (int e = 0; e < 8; ++e)
            hw[e] = (u32)f2bf(vals[2*e]) | ((u32)f2bf(vals[2*e+1]) << 16);
        const size_t kb2 = ((size_t)b * N_ + n0 + r) * C_ + o0 + och;
        reinterpret_cast<uint4*>(ktp + kb2)[0] = make_uint4(hw[0], hw[1], hw[2], hw[3]);
        reinterpret_cast<uint4*>(ktp + kb2)[1] = make_uint4(hw[4], hw[5], hw[6], hw[7]);
    }
}

// ---------------------------------------------------------------------------
// Kernel 2: MFMA flash attention (swapped QK^T), split-KV across 4 waves.
// Grid: 1024 blocks (b = gid&7 -> batch pinned per XCD), 256 threads.
// Block owns 16 query rows (n0). Wave w handles m-chunks {32*(4it+w)}.
// SWAPPED S: s = MFMA(A=K_frag, B=Q_frag) -> lane l, reg j holds
//   S[m = m0 + 4*lg + j (+16 for s1)][n = n0 + lx]   (lx=l&15, lg=l>>4)
// => softmax row n = lx is LANE-LOCAL (reduce over lanes {l, l^16, l^32, l^48});
//    alpha / lrun / 1/l are per-lane, no redistribution needed.
// out acc: lane l holds out[c = 16*ct + 4*lg + j][n = n0 + lx]  (16 x f32x4).
// ---------------------------------------------------------------------------
__global__ __launch_bounds__(256, 2) void attn_k(
    const u16* __restrict__ qt, const u16* __restrict__ kt,
    const u16* __restrict__ vt, const float* __restrict__ xres,
    float* __restrict__ out)
{
    const int gid = blockIdx.x;
    const int b   = gid & 7;
    const int n0  = (gid >> 3) * 16;
    const int tid = threadIdx.x;
    const int w   = tid >> 6;
    const int l   = tid & 63;
    const int lx  = l & 15;
    const int lg  = l >> 4;

    __shared__ float mergebuf[4][256][17];   // 69632 B
    __shared__ u32   pbuf[4][32][17];        //  8704 B  (P as bf16 in low 16b)
    __shared__ float mlbuf[4][2][16];        //   512 B
    __shared__ float wbuf[4][16];            //   256 B

    // Q fragments (B-operand): lane holds Q[n0+lx][k = kb*32 + lg*8 + e]
    const u16* qrow = qt + ((size_t)b * N_ + n0 + lx) * C_ + lg * 8;
    bf16x8 qf[8];
    #pragma unroll
    for (int kb = 0; kb < 8; ++kb) qf[kb] = ldg8(qrow + kb * 32);

    const u16* krow = kt + ((size_t)b * N_ + lx) * C_ + lg * 8;
    const u16* vrow = vt + ((size_t)b * C_ + lx) * N_ + lg * 8;

    f32x4 acc[16];
    #pragma unroll
    for (int ct = 0; ct < 16; ++ct) acc[ct] = (f32x4){0.f, 0.f, 0.f, 0.f};
    float mrun = -1e30f, lrun = 0.f;   // row n = lx (replicated over 4 lanes)

    #pragma unroll 1
    for (int it = 0; it < 16; ++it) {
        const int m0 = (it * 4 + w) * 32;

        // ---- S^T chunk: A = K rows (m), B = Q rows (n) ----
        f32x4 s0 = (f32x4){0.f,0.f,0.f,0.f}, s1 = (f32x4){0.f,0.f,0.f,0.f};
        const u16* k0 = krow + (size_t)m0 * C_;
        #pragma unroll
        for (int kb = 0; kb < 8; ++kb) {
            bf16x8 a0 = ldg8(k0 + kb * 32);            // K row m0+lx
            bf16x8 a1 = ldg8(k0 + 16 * C_ + kb * 32);  // K row m0+16+lx
            s0 = MFMA(a0, qf[kb], s0);
            s1 = MFMA(a1, qf[kb], s1);
        }

        // ---- online softmax, row n = lx (lane-local state) ----
        float mx = fmaxf(fmaxf(fmaxf(s0[0], s0[1]), fmaxf(s0[2], s0[3])),
                         fmaxf(fmaxf(s1[0], s1[1]), fmaxf(s1[2], s1[3])));
        mx = fmaxf(mx, __shfl_xor(mx, 16));
        mx = fmaxf(mx, __shfl_xor(mx, 32));
        const float mnew  = fmaxf(mrun, mx);
        const float alpha = __expf(mrun - mnew);
        float p0[4], p1[4], r = 0.f;
        #pragma unroll
        for (int j = 0; j < 4; ++j) {
            p0[j] = __expf(s0[j] - mnew);
            p1[j] = __expf(s1[j] - mnew);
            r += p0[j] + p1[j];
        }
        r += __shfl_xor(r, 16);
        r += __shfl_xor(r, 32);
        lrun = lrun * alpha + r;
        mrun = mnew;

        // rescale acc by own alpha (acc col n == lx == alpha's row)
        if (__any(alpha != 1.0f)) {
            #pragma unroll
            for (int ct = 0; ct < 16; ++ct) {
                acc[ct][0] *= alpha; acc[ct][1] *= alpha;
                acc[ct][2] *= alpha; acc[ct][3] *= alpha;
            }
        }

        // ---- P exchange: pbuf[w][m-slot][n] (bf16 in low 16 bits) ----
        #pragma unroll
        for (int j = 0; j < 4; ++j) {
            pbuf[w][4*lg + j][lx]      = (u32)f2bf(p0[j]);
            pbuf[w][16 + 4*lg + j][lx] = (u32)f2bf(p1[j]);
        }
        bf16x8 pf;   // B-operand: lane l elem e = P[m-slot lg*8+e][n=lx]
        #pragma unroll
        for (int e = 0; e < 8; ++e)
            pf[e] = (short)(u16)pbuf[w][lg*8 + e][lx];

        // ---- PV: acc[ct] += V[c = 16ct+row][m-chunk] x P ----
        const u16* v0 = vrow + m0;
        #pragma unroll
        for (int ct = 0; ct < 16; ++ct) {
            bf16x8 ah = ldg8(v0 + (size_t)ct * 16 * N_);
            acc[ct] = MFMA(ah, pf, acc[ct]);
        }
    }

    // ---- merge 4 split-KV partials ----
    #pragma unroll
    for (int ct = 0; ct < 16; ++ct)
        #pragma unroll
        for (int j = 0; j < 4; ++j)
            mergebuf[w][16*ct + 4*lg + j][lx] = acc[ct][j];
    if (lg == 0) {                       // lanes 0..15: row lx
        mlbuf[w][0][lx] = mrun;
        mlbuf[w][1][lx] = lrun;
    }
    __syncthreads();
    if (tid < 16) {
        const int xi = tid;
        const float m0_ = mlbuf[0][0][xi], m1_ = mlbuf[1][0][xi];
        const float m2_ = mlbuf[2][0][xi], m3_ = mlbuf[3][0][xi];
        const float M = fmaxf(fmaxf(m0_, m1_), fmaxf(m2_, m3_));
        const float e0 = __expf(m0_ - M), e1 = __expf(m1_ - M);
        const float e2 = __expf(m2_ - M), e3 = __expf(m3_ - M);
        const float denom = e0 * mlbuf[0][1][xi] + e1 * mlbuf[1][1][xi]
                          + e2 * mlbuf[2][1][xi] + e3 * mlbuf[3][1][xi];
        const float inv = 1.0f / denom;
        wbuf[0][xi] = e0 * inv; wbuf[1][xi] = e1 * inv;
        wbuf[2][xi] = e2 * inv; wbuf[3][xi] = e3 * inv;
    }
    __syncthreads();

    // ---- epilogue: combine + residual + store (thread = channel c) ----
    const int c = tid;
    const size_t obase = ((size_t)b * C_ + c) * N_ + n0;
    #pragma unroll
    for (int u = 0; u < 4; ++u) {
        float4 res = *(const float4*)(xres + obase + u*4);
        float4 o;
        #pragma unroll
        for (int j = 0; j < 4; ++j) {
            const int xi = u*4 + j;
            const float v = wbuf[0][xi] * mergebuf[0][c][xi]
                          + wbuf[1][xi] * mergebuf[1][c][xi]
                          + wbuf[2][xi] * mergebuf[2][c][xi]
                          + wbuf[3][xi] * mergebuf[3][c][xi];
            (&o.x)[j] = v + (&res.x)[j];
        }
        *(float4*)(out + obase + u*4) = o;
    }
}

// ---------------------------------------------------------------------------
extern "C" void kernel_launch(void* const* d_in, const int* in_sizes, int n_in,
                              void* d_out, int out_size, void* d_ws, size_t ws_size,
                              hipStream_t stream) {
    const float* x  = (const float*)d_in[0];
    const float* Wq = (const float*)d_in[1];
    const float* bq = (const float*)d_in[2];
    const float* Wk = (const float*)d_in[3];
    const float* bk = (const float*)d_in[4];
    const float* Wv = (const float*)d_in[5];
    const float* bv = (const float*)d_in[6];
    float* outp = (float*)d_out;

    const size_t plane = (size_t)B_ * C_ * N_;   // 4,194,304 elements
    u16* qt = (u16*)d_ws;        // [B][N][C] bf16, pre-scaled 1/16
    u16* kt = qt + plane;        // [B][N][C]
    u16* vt = kt + plane;        // [B][C][N]  -> total 3*plane*2 = 25,165,824 B

    dim3 g1(N_/64, C_/64, B_);
    qkv_k<<<g1, 256, 0, stream>>>(x, Wq, bq, Wk, bk, Wv, bv, qt, kt, vt);

    attn_k<<<1024, 256, 0, stream>>>(qt, kt, vt, x, outp);
}